// Round 3
// baseline (1267.480 us; speedup 1.0000x reference)
//
#include <hip/hip_runtime.h>
#include <stdint.h>

// RPN GT matcher — exact JAX-semantics reimplementation.
// RNG variant ladder (one bench per round):
//   R1: partitionable, bits = o1 (low word)   -> FAIL absmax 2.0
//   R2: partitionable, bits = o0 (high word)  -> FAIL absmax 2.0
//   R3: partitionable, bits = o0 ^ o1         -> this round
//       (matches jax/_src/prng.py _threefry_random_bits_partitionable:
//        bit_width in [8,16,32] -> convert(bits1 ^ bits2))
//   fallback if absmax=2 again: JAX_PARTITIONABLE=0 (legacy counter layout).
#define JAX_PARTITIONABLE 1
#define BITS_MODE 2   // 0: o0  1: o1  2: o0^o1
#define CTR_ORDER 0   // 0: counter pair (0, i); 1: (i, 0)

#define NANCH   262144      // anchors
#define NB      4           // batch
#define NG      64          // gt boxes per image
#define TGT_FG  153         // int(0.3*512)
#define SB      512         // sample batch
#define IDXMASK 262143u     // 2^18-1, anchor-index field in sort keys

// ---- workspace layout (bytes); harness poisons ws with 0xAA each launch ----
#define WS_G2A      0                         // NB*NG f32 (atomicMax as u32)
#define WS_NUMPOS   1024                      // NB i32
#define WS_NEGCNT   1088                      // NB i32
#define WS_KTH      1152                      // NB u64
#define WS_TBG      1216                      // NB i32
#define WS_DOSAMP   1280                      // NB i32
#define WS_SAMPKEY  2048                      // NB*SB u64 (ends 18432)
#define WS_ZERO_WORDS 4608                    // zero [0,18432) as u32
#define WS_A2G      32768                     // NB*NANCH u8
#define WS_NEG      (WS_A2G + NB*NANCH)       // NB*NANCH u32
#define WS_POS      (WS_NEG + NB*NANCH*4)     // NB*NANCH u64  (~13.1 MB total)

struct RngKeys { uint32_t kp[NB][2]; uint32_t kn[NB][2]; };

// ---------------- threefry2x32-20, exactly as jax/_src/prng.py -------------
#define TFR(r) { x0 += x1; x1 = (x1 << (r)) | (x1 >> (32 - (r))); x1 ^= x0; }
__host__ __device__ inline void tf2x32(uint32_t k0, uint32_t k1,
                                       uint32_t x0, uint32_t x1,
                                       uint32_t &o0, uint32_t &o1) {
  uint32_t k2 = k0 ^ k1 ^ 0x1BD11BDAu;
  x0 += k0; x1 += k1;
  TFR(13) TFR(15) TFR(26) TFR(6)   x0 += k1; x1 += k2 + 1u;
  TFR(17) TFR(29) TFR(16) TFR(24)  x0 += k2; x1 += k0 + 2u;
  TFR(13) TFR(15) TFR(26) TFR(6)   x0 += k0; x1 += k1 + 3u;
  TFR(17) TFR(29) TFR(16) TFR(24)  x0 += k1; x1 += k2 + 4u;
  TFR(13) TFR(15) TFR(26) TFR(6)   x0 += k2; x1 += k0 + 5u;
  o0 = x0; o1 = x1;
}

// hash with per-element counter i (partitionable counter-mode), both words
__host__ __device__ inline void tf_ctr(uint32_t k0, uint32_t k1, uint32_t i,
                                       uint32_t &o0, uint32_t &o1) {
#if CTR_ORDER
  tf2x32(k0, k1, i, 0u, o0, o1);
#else
  tf2x32(k0, k1, 0u, i, o0, o1);
#endif
}

// 32-bit random draw for flat element index (uniform / gumbel bits source)
__device__ __forceinline__ uint32_t draw_bits(uint32_t k0, uint32_t k1,
                                              uint32_t idx, uint32_t total_half) {
  uint32_t o0, o1;
#if JAX_PARTITIONABLE
  (void)total_half;
  tf_ctr(k0, k1, idx, o0, o1);
#if BITS_MODE == 0
  return o0;
#elif BITS_MODE == 1
  return o1;
#else
  return o0 ^ o1;
#endif
#else
  if (idx < total_half) { tf2x32(k0, k1, idx, idx + total_half, o0, o1); return o0; }
  tf2x32(k0, k1, idx - total_half, idx, o0, o1); return o1;
#endif
}

// ------------- IoU, bit-identical across passes (no FP contraction) --------
__device__ __forceinline__ float box_area(float x1, float y1, float x2, float y2) {
#pragma clang fp contract(off)
  return ((x2 - x1) + 1.0f) * ((y2 - y1) + 1.0f);
}

__device__ __forceinline__ float iou_pair(float ax1, float ay1, float ax2, float ay2,
                                          float areaA, float gx1, float gy1,
                                          float gx2, float gy2, float areaB) {
#pragma clang fp contract(off)
  float ltx = fmaxf(ax1, gx1), lty = fmaxf(ay1, gy1);
  float rbx = fminf(ax2, gx2), rby = fminf(ay2, gy2);
  float w = fmaxf((rbx - ltx) + 1.0f, 0.0f);
  float h = fmaxf((rby - lty) + 1.0f, 0.0f);
  float inter = w * h;
  return inter / ((areaA + areaB) - inter);
}

// wave-aggregated list append (1 atomic per wave instead of per lane)
__device__ __forceinline__ int wave_push(int* counter) {
  unsigned long long mask = __ballot(1);
  int lane   = threadIdx.x & 63;
  int leader = __ffsll(mask) - 1;
  int prefix = __popcll(mask & ((1ull << lane) - 1ull));
  int total  = __popcll(mask);
  int base = 0;
  if (lane == leader) base = atomicAdd(counter, total);
  base = __shfl(base, leader, 64);
  return base + prefix;
}

// ---------------------------------------------------------------------------
__global__ __launch_bounds__(256) void k_init(unsigned int* w) {
  int i = blockIdx.x * 256 + threadIdx.x;
  if (i < WS_ZERO_WORDS) w[i] = 0u;
}

// Pass A: g2a_max[b][j] = max_a masked_iou. Lanes = gt index, serial anchors.
__global__ __launch_bounds__(256) void k_g2amax(
    const float4* __restrict__ boxes, const float4* __restrict__ gtb,
    const int* __restrict__ gti, const float* __restrict__ iminfo,
    unsigned int* __restrict__ g2a_u32) {
  int bx = blockIdx.x;
  int b = bx >> 8, chunk = bx & 255;          // NANCH/1024 = 256 chunks/batch
  int t = threadIdx.x, j = t & 63, sub = t >> 6;
  float4 g = gtb[b * NG + j];
  bool valid = (gti[b * NG + j] == 0);
  float areaB = box_area(g.x, g.y, g.z, g.w);
  float thrx = iminfo[b * 3 + 1] + 1.0f;      // im_w + STRADDLE + 1
  float thry = iminfo[b * 3 + 0] + 1.0f;      // im_h + STRADDLE + 1
  float m = 0.0f;
  int base = chunk * 1024 + sub * 256;
  #pragma unroll 2
  for (int i = 0; i < 256; ++i) {
    float4 bb = boxes[base + i];              // same addr across wave: broadcast
    bool inside = (bb.x >= -0.0f) && (bb.y >= -0.0f) && (bb.z < thrx) && (bb.w < thry);
    float areaA = box_area(bb.x, bb.y, bb.z, bb.w);
    float v = iou_pair(bb.x, bb.y, bb.z, bb.w, areaA, g.x, g.y, g.z, g.w, areaB);
    v = (inside && valid) ? v : 0.0f;
    m = fmaxf(m, v);
  }
  __shared__ float red[4][64];
  red[sub][j] = m;
  __syncthreads();
  if (t < 64) {
    float mm = fmaxf(fmaxf(red[0][t], red[1][t]), fmaxf(red[2][t], red[3][t]));
    atomicMax(&g2a_u32[b * NG + t], __float_as_uint(mm));  // iou>=0: u32 order==f32
  }
}

// Pass B: labels init, argmax gt, with_max, pos/neg compaction with RNG keys.
__global__ __launch_bounds__(256) void k_label(
    const float4* __restrict__ boxes, const float4* __restrict__ gtb,
    const int* __restrict__ gti, const float* __restrict__ iminfo,
    const float* __restrict__ g2a, float* __restrict__ labels,
    unsigned char* __restrict__ a2g, unsigned long long* __restrict__ pos_keys,
    unsigned int* __restrict__ neg_list, int* __restrict__ num_pos,
    int* __restrict__ neg_cnt, RngKeys rk) {
  int bx = blockIdx.x;
  int b = bx >> 10, blk = bx & 1023;          // NANCH/256 = 1024 blocks/batch
  int t = threadIdx.x;
  __shared__ float4 sg[NG];
  __shared__ float sab[NG], sval[NG], sadj[NG];
  if (t < NG) {
    float4 g = gtb[b * NG + t];
    sg[t] = g;
    sab[t] = box_area(g.x, g.y, g.z, g.w);
    sval[t] = (gti[b * NG + t] == 0) ? 1.0f : 0.0f;
    float gm = g2a[b * NG + t];
    sadj[t] = (gm == 0.0f) ? 1.0f : gm;       // avoid matching all-zero cols
  }
  __syncthreads();
  int a = blk * 256 + t;
  float4 bb = boxes[a];
  float thrx = iminfo[b * 3 + 1] + 1.0f, thry = iminfo[b * 3 + 0] + 1.0f;
  bool inside = (bb.x >= -0.0f) && (bb.y >= -0.0f) && (bb.z < thrx) && (bb.w < thry);
  float areaA = box_area(bb.x, bb.y, bb.z, bb.w);
  float maxv = 0.0f; int amax = 0; bool wm = false;
  #pragma unroll 8
  for (int j = 0; j < NG; ++j) {
    float4 g = sg[j];
    float v = iou_pair(bb.x, bb.y, bb.z, bb.w, areaA, g.x, g.y, g.z, g.w, sab[j]);
    v = (inside && (sval[j] != 0.0f)) ? v : 0.0f;
    wm = wm || (v == sadj[j]);                 // ensure_closest_box
    if (v > maxv) { maxv = v; amax = j; }      // first-max (== jnp.argmax)
  }
  bool pos = inside && (wm || (maxv >= 0.5f));
  bool neg = inside && (maxv < 0.3f);
  labels[b * NANCH + a] = pos ? 1.0f : -1.0f;
  a2g[b * NANCH + a] = (unsigned char)amax;
  if (pos) {
    // prio = uniform(kp,(n,)) -> monotone in bits>>9; key: prio desc, idx asc
    uint32_t bits = draw_bits(rk.kp[b][0], rk.kp[b][1], (uint32_t)a, NANCH / 2u);
    unsigned long long key =
        (((unsigned long long)(bits >> 9)) << 18) | (unsigned long long)(IDXMASK - (uint32_t)a);
    int p = wave_push(&num_pos[b]);
    pos_keys[(size_t)b * NANCH + p] = key;
  }
  if (neg) {
    int q = wave_push(&neg_cnt[b]);
    neg_list[(size_t)b * NANCH + q] = (unsigned int)a;
  }
}

// 41-bit MSB radix-select: kth[b] = 153rd-largest pos key (0 if np<=153).
__global__ __launch_bounds__(256) void k_select(
    const unsigned long long* __restrict__ pos_keys, const int* __restrict__ num_pos,
    const int* __restrict__ neg_cnt, unsigned long long* __restrict__ kth,
    int* __restrict__ tbg, int* __restrict__ dosamp) {
  int b = blockIdx.x, t = threadIdx.x;
  __shared__ int cnt[256];
  int np = num_pos[b];
  int nf = np < TGT_FG ? np : TGT_FG;
  int targ = SB - nf;
  if (t == 0) { tbg[b] = targ; dosamp[b] = (neg_cnt[b] > targ) ? 1 : 0; }
  if (np <= TGT_FG) { if (t == 0) kth[b] = 0ull; return; }
  const unsigned long long* keys = pos_keys + (size_t)b * NANCH;
  unsigned long long pref = 0ull;
  int r = TGT_FG;
  for (int bit = 40; bit >= 0; --bit) {
    unsigned long long cand = pref | (1ull << bit);
    unsigned long long mask = ~((1ull << bit) - 1ull);
    int c = 0;
    for (int i = t; i < np; i += 256) c += ((keys[i] & mask) == cand) ? 1 : 0;
    cnt[t] = c; __syncthreads();
    for (int st = 128; st > 0; st >>= 1) { if (t < st) cnt[t] += cnt[t + st]; __syncthreads(); }
    int total = cnt[0]; __syncthreads();
    if (total >= r) pref = cand; else r -= total;
  }
  if (t == 0) kth[b] = pref;
}

// Disable positives below the top-153 priority threshold.
__global__ __launch_bounds__(256) void k_disable(
    const unsigned long long* __restrict__ pos_keys, const int* __restrict__ num_pos,
    const unsigned long long* __restrict__ kth, float* __restrict__ labels) {
  int b = blockIdx.x >> 6, blk = blockIdx.x & 63;
  int np = num_pos[b];
  if (np <= TGT_FG) return;
  unsigned long long K = kth[b];
  for (int i = blk * 256 + threadIdx.x; i < np; i += 64 * 256) {
    unsigned long long key = pos_keys[(size_t)b * NANCH + i];
    if (key < K) {
      int a = (int)(IDXMASK - (uint32_t)(key & (unsigned long long)IDXMASK));
      labels[b * NANCH + a] = -1.0f;
    }
  }
}

// categorical(kn, neg?0:-1e9, shape=(512,)) == per-draw key-argmax over negs.
// gumbel is strictly monotone in bits>>9 among top candidates; exact-bit ties
// -> first (smallest) flat index, encoded via IDXMASK-a in the key low bits.
#define CC 4
__global__ __launch_bounds__(256) void k_cat(
    const unsigned int* __restrict__ neg_list, const int* __restrict__ neg_cnt,
    unsigned long long* __restrict__ samp_key, RngKeys rk) {
  int bx = blockIdx.x;
  int c = bx & (CC - 1);
  int s = (bx >> 2) & (SB - 1);
  int b = bx >> 11;
  int nn = neg_cnt[b];
  uint32_t k0 = rk.kn[b][0], k1 = rk.kn[b][1];
  uint32_t mbase = (uint32_t)s * (uint32_t)NANCH;
  unsigned long long best = 0ull;
  for (int i = c * 256 + threadIdx.x; i < nn; i += CC * 256) {
    uint32_t a = neg_list[(size_t)b * NANCH + i];
    uint32_t bits = draw_bits(k0, k1, mbase + a, (uint32_t)SB * (uint32_t)NANCH / 2u);
    unsigned long long key =
        (((unsigned long long)(bits >> 9)) << 18) | (unsigned long long)(IDXMASK - a);
    if (key > best) best = key;
  }
  __shared__ unsigned long long red[256];
  red[threadIdx.x] = best;
  __syncthreads();
  for (int st = 128; st > 0; st >>= 1) {
    if (threadIdx.x < st) { if (red[threadIdx.x + st] > red[threadIdx.x]) red[threadIdx.x] = red[threadIdx.x + st]; }
    __syncthreads();
  }
  if (threadIdx.x == 0) atomicMax(&samp_key[b * SB + s], red[0]);
}

// Set sampled negatives to 0 (after fg-disable, matching reference order).
__global__ __launch_bounds__(256) void k_scatter(
    const unsigned long long* __restrict__ samp_key, const int* __restrict__ tbg,
    const int* __restrict__ dosamp, float* __restrict__ labels) {
  int b = blockIdx.x >> 1;
  int s = ((blockIdx.x & 1) << 8) | threadIdx.x;
  if (!dosamp[b]) return;
  if (s < tbg[b]) {
    unsigned long long key = samp_key[b * SB + s];
    int a = (int)(IDXMASK - (uint32_t)(key & (unsigned long long)IDXMASK));
    labels[b * NANCH + a] = 0.0f;
  }
}

// bbox_transform_inv for final positives; zeros elsewhere.
__global__ __launch_bounds__(256) void k_targets(
    const float4* __restrict__ boxes, const float4* __restrict__ gtb,
    const unsigned char* __restrict__ a2g, const float* __restrict__ labels,
    float4* __restrict__ tout) {
  int bx = blockIdx.x;
  int b = bx >> 10, blk = bx & 1023;
  int a = blk * 256 + threadIdx.x;
  float lab = labels[b * NANCH + a];
  float4 o = make_float4(0.f, 0.f, 0.f, 0.f);
  if (lab > 0.0f) {
    float4 e = boxes[a];
    float4 g = gtb[b * NG + a2g[b * NANCH + a]];
    float ew = e.z - e.x + 1.0f, eh = e.w - e.y + 1.0f;
    float ecx = e.x + 0.5f * ew, ecy = e.y + 0.5f * eh;
    float gw = g.z - g.x + 1.0f, gh = g.w - g.y + 1.0f;
    float gcx = g.x + 0.5f * gw, gcy = g.y + 0.5f * gh;
    o.x = (gcx - ecx) / ew;
    o.y = (gcy - ecy) / eh;
    o.z = logf(gw / ew);
    o.w = logf(gh / eh);
  }
  tout[(size_t)b * NANCH + a] = o;
}

// ---------------------------------------------------------------------------
extern "C" void kernel_launch(void* const* d_in, const int* in_sizes, int n_in,
                              void* d_out, int out_size, void* d_ws, size_t ws_size,
                              hipStream_t stream) {
  const float4* boxes  = (const float4*)d_in[0];
  const float4* gtb    = (const float4*)d_in[1];
  // d_in[2] = gt_labels: unused, exactly like the reference
  const int*    gti    = (const int*)d_in[3];
  const float*  iminfo = (const float*)d_in[4];
  float*  labels = (float*)d_out;                       // [B][N] as f32
  float4* tout   = (float4*)(labels + (size_t)NB * NANCH); // [B][N][4]

  char* wsb = (char*)d_ws;  // needs ~13.1 MB
  unsigned int*       g2a_u32  = (unsigned int*)(wsb + WS_G2A);
  float*              g2a_f    = (float*)(wsb + WS_G2A);
  int*                num_pos  = (int*)(wsb + WS_NUMPOS);
  int*                neg_cnt  = (int*)(wsb + WS_NEGCNT);
  unsigned long long* kth      = (unsigned long long*)(wsb + WS_KTH);
  int*                tbg      = (int*)(wsb + WS_TBG);
  int*                dosamp   = (int*)(wsb + WS_DOSAMP);
  unsigned long long* samp_key = (unsigned long long*)(wsb + WS_SAMPKEY);
  unsigned char*      a2g      = (unsigned char*)(wsb + WS_A2G);
  unsigned int*       neg_list = (unsigned int*)(wsb + WS_NEG);
  unsigned long long* pos_keys = (unsigned long long*)(wsb + WS_POS);

  // Host-side key derivation: root=(0,42); split(root,4) -> per-image key;
  // split(key_b,2) -> (kp, kn). Split keys are the FULL 64-bit outputs
  // (no XOR — _threefry_split_foldlike stacks both words).
  RngKeys rk;
#if JAX_PARTITIONABLE
  for (int b = 0; b < NB; ++b) {
    uint32_t a0, a1;
    tf_ctr(0u, 42u, (uint32_t)b, a0, a1);                // keys[b]
    tf_ctr(a0, a1, 0u, rk.kp[b][0], rk.kp[b][1]);        // subkey 0 = kp
    tf_ctr(a0, a1, 1u, rk.kn[b][0], rk.kn[b][1]);        // subkey 1 = kn
  }
#else
  {
    uint32_t o0[4], o1[4];
    for (int i = 0; i < 4; ++i) tf2x32(0u, 42u, (uint32_t)i, (uint32_t)(i + 4), o0[i], o1[i]);
    uint32_t keys[NB][2] = {{o0[0], o0[1]}, {o0[2], o0[3]}, {o1[0], o1[1]}, {o1[2], o1[3]}};
    for (int b = 0; b < NB; ++b) {
      uint32_t p0, p1, q0, q1;
      tf2x32(keys[b][0], keys[b][1], 0u, 2u, p0, q0);
      tf2x32(keys[b][0], keys[b][1], 1u, 3u, p1, q1);
      rk.kp[b][0] = p0; rk.kp[b][1] = p1;
      rk.kn[b][0] = q0; rk.kn[b][1] = q1;
    }
  }
#endif

  k_init   <<<18, 256, 0, stream>>>((unsigned int*)wsb);
  k_g2amax <<<NB * (NANCH / 1024), 256, 0, stream>>>(boxes, gtb, gti, iminfo, g2a_u32);
  k_label  <<<NB * (NANCH / 256), 256, 0, stream>>>(boxes, gtb, gti, iminfo, g2a_f,
                                                    labels, a2g, pos_keys, neg_list,
                                                    num_pos, neg_cnt, rk);
  k_select <<<NB, 256, 0, stream>>>(pos_keys, num_pos, neg_cnt, kth, tbg, dosamp);
  k_disable<<<NB * 64, 256, 0, stream>>>(pos_keys, num_pos, kth, labels);
  k_cat    <<<NB * SB * CC, 256, 0, stream>>>(neg_list, neg_cnt, samp_key, rk);
  k_scatter<<<NB * 2, 256, 0, stream>>>(samp_key, tbg, dosamp, labels);
  k_targets<<<NB * (NANCH / 256), 256, 0, stream>>>(boxes, gtb, a2g, labels, tout);
}

// Round 4
// 1238.875 us; speedup vs baseline: 1.0231x; 1.0231x over previous
//
#include <hip/hip_runtime.h>
#include <stdint.h>

// RPN GT matcher — exact JAX-semantics reimplementation.
// RNG (verified R3, passed): partitionable counter-mode, counter=(0, flat_idx),
// 32-bit draw = o0 ^ o1; split(key,n)[i] = both words of tf(key,(0,i)).
#define JAX_PARTITIONABLE 1
#define BITS_MODE 2   // o0 ^ o1
#define CTR_ORDER 0   // counter pair (0, i)

#define NANCH   262144      // anchors (== 2^18, required by key packing)
#define NB      4           // batch
#define NG      64          // gt boxes per image
#define TGT_FG  153         // int(0.3*512)
#define SB      512         // sample batch
#define IDXMASK 262143u     // 2^18-1, anchor-index field in sort keys

// ---- workspace layout (bytes); harness poisons ws with 0xAA each launch ----
#define WS_G2A      0                         // NB*NG f32 (atomicMax as u32)
#define WS_NUMPOS   1024                      // NB i32
#define WS_NEGCNT   1088                      // NB i32
#define WS_KTH      1152                      // NB u64
#define WS_TBG      1216                      // NB i32
#define WS_DOSAMP   1280                      // NB i32
#define WS_SAMPKEY  2048                      // NB*SB u64 (ends 18432)
#define WS_ZERO_WORDS 4608                    // zero [0,18432) as u32
#define WS_A2G      32768                     // NB*NANCH u8
#define WS_NEG      (WS_A2G + NB*NANCH)       // NB*NANCH u32
#define WS_POS      (WS_NEG + NB*NANCH*4)     // NB*NANCH u64  (~13.1 MB total)

struct RngKeys { uint32_t kp[NB][2]; uint32_t kn[NB][2]; };

// ---------------- threefry2x32-20, exactly as jax/_src/prng.py -------------
#define TFR(r) { x0 += x1; x1 = (x1 << (r)) | (x1 >> (32 - (r))); x1 ^= x0; }
__host__ __device__ inline void tf2x32(uint32_t k0, uint32_t k1,
                                       uint32_t x0, uint32_t x1,
                                       uint32_t &o0, uint32_t &o1) {
  uint32_t k2 = k0 ^ k1 ^ 0x1BD11BDAu;
  x0 += k0; x1 += k1;
  TFR(13) TFR(15) TFR(26) TFR(6)   x0 += k1; x1 += k2 + 1u;
  TFR(17) TFR(29) TFR(16) TFR(24)  x0 += k2; x1 += k0 + 2u;
  TFR(13) TFR(15) TFR(26) TFR(6)   x0 += k0; x1 += k1 + 3u;
  TFR(17) TFR(29) TFR(16) TFR(24)  x0 += k1; x1 += k2 + 4u;
  TFR(13) TFR(15) TFR(26) TFR(6)   x0 += k2; x1 += k0 + 5u;
  o0 = x0; o1 = x1;
}

// hash with per-element counter i (partitionable counter-mode), both words
__host__ __device__ inline void tf_ctr(uint32_t k0, uint32_t k1, uint32_t i,
                                       uint32_t &o0, uint32_t &o1) {
#if CTR_ORDER
  tf2x32(k0, k1, i, 0u, o0, o1);
#else
  tf2x32(k0, k1, 0u, i, o0, o1);
#endif
}

// 32-bit random draw for flat element index (uniform / gumbel bits source)
__device__ __forceinline__ uint32_t draw_bits(uint32_t k0, uint32_t k1,
                                              uint32_t idx, uint32_t total_half) {
  uint32_t o0, o1;
  (void)total_half;
  tf_ctr(k0, k1, idx, o0, o1);
  return o0 ^ o1;
}

// ---- fast threefry for the categorical hot loop: 1-op rotate guaranteed ----
#define ROTL1(x, r) __builtin_amdgcn_alignbit((x), (x), 32 - (r))
#define TFQ(r) { x0 += x1; x1 = ROTL1(x1, r); x1 ^= x0; }
// caller pre-applies +k0 to x0 and +k1 to x1 (x0 ctr word is 0 -> x0 = k0)
__device__ __forceinline__ uint32_t tf_bits_fast(uint32_t k0, uint32_t k1,
                                                 uint32_t k2, uint32_t x0,
                                                 uint32_t x1) {
  TFQ(13) TFQ(15) TFQ(26) TFQ(6)   x0 += k1; x1 += k2 + 1u;
  TFQ(17) TFQ(29) TFQ(16) TFQ(24)  x0 += k2; x1 += k0 + 2u;
  TFQ(13) TFQ(15) TFQ(26) TFQ(6)   x0 += k0; x1 += k1 + 3u;
  TFQ(17) TFQ(29) TFQ(16) TFQ(24)  x0 += k1; x1 += k2 + 4u;
  TFQ(13) TFQ(15) TFQ(26) TFQ(6)   x0 += k2; x1 += k0 + 5u;
  return x0 ^ x1;
}

// ------------- IoU, bit-identical across passes (no FP contraction) --------
__device__ __forceinline__ float box_area(float x1, float y1, float x2, float y2) {
#pragma clang fp contract(off)
  return ((x2 - x1) + 1.0f) * ((y2 - y1) + 1.0f);
}

__device__ __forceinline__ float iou_pair(float ax1, float ay1, float ax2, float ay2,
                                          float areaA, float gx1, float gy1,
                                          float gx2, float gy2, float areaB) {
#pragma clang fp contract(off)
  float ltx = fmaxf(ax1, gx1), lty = fmaxf(ay1, gy1);
  float rbx = fminf(ax2, gx2), rby = fminf(ay2, gy2);
  float w = fmaxf((rbx - ltx) + 1.0f, 0.0f);
  float h = fmaxf((rby - lty) + 1.0f, 0.0f);
  float inter = w * h;
  return inter / ((areaA + areaB) - inter);
}

// wave-aggregated list append (1 atomic per wave instead of per lane)
__device__ __forceinline__ int wave_push(int* counter) {
  unsigned long long mask = __ballot(1);
  int lane   = threadIdx.x & 63;
  int leader = __ffsll(mask) - 1;
  int prefix = __popcll(mask & ((1ull << lane) - 1ull));
  int total  = __popcll(mask);
  int base = 0;
  if (lane == leader) base = atomicAdd(counter, total);
  base = __shfl(base, leader, 64);
  return base + prefix;
}

// ---------------------------------------------------------------------------
__global__ __launch_bounds__(256) void k_init(unsigned int* w) {
  int i = blockIdx.x * 256 + threadIdx.x;
  if (i < WS_ZERO_WORDS) w[i] = 0u;
}

// Pass A: g2a_max[b][j] = max_a masked_iou. Lanes = gt index, serial anchors.
__global__ __launch_bounds__(256) void k_g2amax(
    const float4* __restrict__ boxes, const float4* __restrict__ gtb,
    const int* __restrict__ gti, const float* __restrict__ iminfo,
    unsigned int* __restrict__ g2a_u32) {
  int bx = blockIdx.x;
  int b = bx >> 8, chunk = bx & 255;          // NANCH/1024 = 256 chunks/batch
  int t = threadIdx.x, j = t & 63, sub = t >> 6;
  float4 g = gtb[b * NG + j];
  bool valid = (gti[b * NG + j] == 0);
  float areaB = box_area(g.x, g.y, g.z, g.w);
  float thrx = iminfo[b * 3 + 1] + 1.0f;      // im_w + STRADDLE + 1
  float thry = iminfo[b * 3 + 0] + 1.0f;      // im_h + STRADDLE + 1
  float m = 0.0f;
  int base = chunk * 1024 + sub * 256;
  #pragma unroll 2
  for (int i = 0; i < 256; ++i) {
    float4 bb = boxes[base + i];              // same addr across wave: broadcast
    bool inside = (bb.x >= -0.0f) && (bb.y >= -0.0f) && (bb.z < thrx) && (bb.w < thry);
    float areaA = box_area(bb.x, bb.y, bb.z, bb.w);
    float v = iou_pair(bb.x, bb.y, bb.z, bb.w, areaA, g.x, g.y, g.z, g.w, areaB);
    v = (inside && valid) ? v : 0.0f;
    m = fmaxf(m, v);
  }
  __shared__ float red[4][64];
  red[sub][j] = m;
  __syncthreads();
  if (t < 64) {
    float mm = fmaxf(fmaxf(red[0][t], red[1][t]), fmaxf(red[2][t], red[3][t]));
    atomicMax(&g2a_u32[b * NG + t], __float_as_uint(mm));  // iou>=0: u32 order==f32
  }
}

// Pass B: labels init, argmax gt, with_max, pos/neg compaction with RNG keys.
__global__ __launch_bounds__(256) void k_label(
    const float4* __restrict__ boxes, const float4* __restrict__ gtb,
    const int* __restrict__ gti, const float* __restrict__ iminfo,
    const float* __restrict__ g2a, float* __restrict__ labels,
    unsigned char* __restrict__ a2g, unsigned long long* __restrict__ pos_keys,
    unsigned int* __restrict__ neg_list, int* __restrict__ num_pos,
    int* __restrict__ neg_cnt, RngKeys rk) {
  int bx = blockIdx.x;
  int b = bx >> 10, blk = bx & 1023;          // NANCH/256 = 1024 blocks/batch
  int t = threadIdx.x;
  __shared__ float4 sg[NG];
  __shared__ float sab[NG], sval[NG], sadj[NG];
  if (t < NG) {
    float4 g = gtb[b * NG + t];
    sg[t] = g;
    sab[t] = box_area(g.x, g.y, g.z, g.w);
    sval[t] = (gti[b * NG + t] == 0) ? 1.0f : 0.0f;
    float gm = g2a[b * NG + t];
    sadj[t] = (gm == 0.0f) ? 1.0f : gm;       // avoid matching all-zero cols
  }
  __syncthreads();
  int a = blk * 256 + t;
  float4 bb = boxes[a];
  float thrx = iminfo[b * 3 + 1] + 1.0f, thry = iminfo[b * 3 + 0] + 1.0f;
  bool inside = (bb.x >= -0.0f) && (bb.y >= -0.0f) && (bb.z < thrx) && (bb.w < thry);
  float areaA = box_area(bb.x, bb.y, bb.z, bb.w);
  float maxv = 0.0f; int amax = 0; bool wm = false;
  #pragma unroll 8
  for (int j = 0; j < NG; ++j) {
    float4 g = sg[j];
    float v = iou_pair(bb.x, bb.y, bb.z, bb.w, areaA, g.x, g.y, g.z, g.w, sab[j]);
    v = (inside && (sval[j] != 0.0f)) ? v : 0.0f;
    wm = wm || (v == sadj[j]);                 // ensure_closest_box
    if (v > maxv) { maxv = v; amax = j; }      // first-max (== jnp.argmax)
  }
  bool pos = inside && (wm || (maxv >= 0.5f));
  bool neg = inside && (maxv < 0.3f);
  labels[b * NANCH + a] = pos ? 1.0f : -1.0f;
  a2g[b * NANCH + a] = (unsigned char)amax;
  if (pos) {
    // prio = uniform(kp,(n,)) -> monotone in bits>>9; key: prio desc, idx asc
    uint32_t bits = draw_bits(rk.kp[b][0], rk.kp[b][1], (uint32_t)a, NANCH / 2u);
    unsigned long long key =
        (((unsigned long long)(bits >> 9)) << 18) | (unsigned long long)(IDXMASK - (uint32_t)a);
    int p = wave_push(&num_pos[b]);
    pos_keys[(size_t)b * NANCH + p] = key;
  }
  if (neg) {
    int q = wave_push(&neg_cnt[b]);
    neg_list[(size_t)b * NANCH + q] = (unsigned int)a;
  }
}

// 41-bit MSB radix-select: kth[b] = 153rd-largest pos key (0 if np<=153).
__global__ __launch_bounds__(256) void k_select(
    const unsigned long long* __restrict__ pos_keys, const int* __restrict__ num_pos,
    const int* __restrict__ neg_cnt, unsigned long long* __restrict__ kth,
    int* __restrict__ tbg, int* __restrict__ dosamp) {
  int b = blockIdx.x, t = threadIdx.x;
  __shared__ int cnt[256];
  int np = num_pos[b];
  int nf = np < TGT_FG ? np : TGT_FG;
  int targ = SB - nf;
  if (t == 0) { tbg[b] = targ; dosamp[b] = (neg_cnt[b] > targ) ? 1 : 0; }
  if (np <= TGT_FG) { if (t == 0) kth[b] = 0ull; return; }
  const unsigned long long* keys = pos_keys + (size_t)b * NANCH;
  unsigned long long pref = 0ull;
  int r = TGT_FG;
  for (int bit = 40; bit >= 0; --bit) {
    unsigned long long cand = pref | (1ull << bit);
    unsigned long long mask = ~((1ull << bit) - 1ull);
    int c = 0;
    for (int i = t; i < np; i += 256) c += ((keys[i] & mask) == cand) ? 1 : 0;
    cnt[t] = c; __syncthreads();
    for (int st = 128; st > 0; st >>= 1) { if (t < st) cnt[t] += cnt[t + st]; __syncthreads(); }
    int total = cnt[0]; __syncthreads();
    if (total >= r) pref = cand; else r -= total;
  }
  if (t == 0) kth[b] = pref;
}

// Disable positives below the top-153 priority threshold.
__global__ __launch_bounds__(256) void k_disable(
    const unsigned long long* __restrict__ pos_keys, const int* __restrict__ num_pos,
    const unsigned long long* __restrict__ kth, float* __restrict__ labels) {
  int b = blockIdx.x >> 6, blk = blockIdx.x & 63;
  int np = num_pos[b];
  if (np <= TGT_FG) return;
  unsigned long long K = kth[b];
  for (int i = blk * 256 + threadIdx.x; i < np; i += 64 * 256) {
    unsigned long long key = pos_keys[(size_t)b * NANCH + i];
    if (key < K) {
      int a = (int)(IDXMASK - (uint32_t)(key & (unsigned long long)IDXMASK));
      labels[b * NANCH + a] = -1.0f;
    }
  }
}

// categorical(kn, neg?0:-1e9, shape=(512,)) == per-draw key-argmax over negs.
// gumbel strictly monotone in bits>>9; exact-bit ties -> smallest flat index
// (encoded IDXMASK-a in key low bits). v2: loop inversion — each thread loads
// one negative and evaluates SPT=8 draws on it (counter (s<<18)|a), keeping 8
// register u64 maxes; alignbit 1-op rotate; x1 init hoisted per draw slot.
#define CC  8    // chunks over the negative list
#define SPT 8    // draws per thread (SB/SPT = 64 draw groups)
__global__ __launch_bounds__(256) void k_cat(
    const unsigned int* __restrict__ neg_list, const int* __restrict__ neg_cnt,
    unsigned long long* __restrict__ samp_key, RngKeys rk) {
  int bx = blockIdx.x;
  int c = bx & (CC - 1);                 // chunk
  int g = (bx >> 3) & 63;                // draw group (SB/SPT = 64)
  int b = bx >> 9;                       // batch
  int nn = neg_cnt[b];
  uint32_t k0 = rk.kn[b][0], k1 = rk.kn[b][1];
  uint32_t k2 = k0 ^ k1 ^ 0x1BD11BDAu;
  uint32_t x1base[SPT];
  unsigned long long best[SPT];
  #pragma unroll
  for (int j = 0; j < SPT; ++j) {
    uint32_t s = (uint32_t)(g * SPT + j);
    x1base[j] = (s << 18) + k1;          // ctr = (s<<18)|a;  x1 = ctr + k1
    best[j] = 0ull;
  }
  const unsigned int* nl = neg_list + (size_t)b * NANCH;
  for (int i = c * 256 + threadIdx.x; i < nn; i += CC * 256) {
    uint32_t a = nl[i];
    uint32_t inv = IDXMASK - a;
    #pragma unroll
    for (int j = 0; j < SPT; ++j) {
      uint32_t bits = tf_bits_fast(k0, k1, k2, k0, x1base[j] + a);
      unsigned long long key =
          (((unsigned long long)(bits >> 9)) << 18) | (unsigned long long)inv;
      if (key > best[j]) best[j] = key;
    }
  }
  // wave butterfly reduction (64 lanes), then cross-wave merge in LDS
  #pragma unroll
  for (int j = 0; j < SPT; ++j) {
    #pragma unroll
    for (int off = 32; off > 0; off >>= 1) {
      unsigned long long o = __shfl_xor(best[j], off, 64);
      if (o > best[j]) best[j] = o;
    }
  }
  __shared__ unsigned long long wred[4][SPT];
  int lane = threadIdx.x & 63, wid = threadIdx.x >> 6;
  if (lane == 0) {
    #pragma unroll
    for (int j = 0; j < SPT; ++j) wred[wid][j] = best[j];
  }
  __syncthreads();
  if (threadIdx.x < SPT) {
    int j = threadIdx.x;
    unsigned long long m = wred[0][j];
    if (wred[1][j] > m) m = wred[1][j];
    if (wred[2][j] > m) m = wred[2][j];
    if (wred[3][j] > m) m = wred[3][j];
    atomicMax(&samp_key[b * SB + g * SPT + j], m);
  }
}

// Set sampled negatives to 0 (after fg-disable, matching reference order).
__global__ __launch_bounds__(256) void k_scatter(
    const unsigned long long* __restrict__ samp_key, const int* __restrict__ tbg,
    const int* __restrict__ dosamp, float* __restrict__ labels) {
  int b = blockIdx.x >> 1;
  int s = ((blockIdx.x & 1) << 8) | threadIdx.x;
  if (!dosamp[b]) return;
  if (s < tbg[b]) {
    unsigned long long key = samp_key[b * SB + s];
    int a = (int)(IDXMASK - (uint32_t)(key & (unsigned long long)IDXMASK));
    labels[b * NANCH + a] = 0.0f;
  }
}

// bbox_transform_inv for final positives; zeros elsewhere.
__global__ __launch_bounds__(256) void k_targets(
    const float4* __restrict__ boxes, const float4* __restrict__ gtb,
    const unsigned char* __restrict__ a2g, const float* __restrict__ labels,
    float4* __restrict__ tout) {
  int bx = blockIdx.x;
  int b = bx >> 10, blk = bx & 1023;
  int a = blk * 256 + threadIdx.x;
  float lab = labels[b * NANCH + a];
  float4 o = make_float4(0.f, 0.f, 0.f, 0.f);
  if (lab > 0.0f) {
    float4 e = boxes[a];
    float4 g = gtb[b * NG + a2g[b * NANCH + a]];
    float ew = e.z - e.x + 1.0f, eh = e.w - e.y + 1.0f;
    float ecx = e.x + 0.5f * ew, ecy = e.y + 0.5f * eh;
    float gw = g.z - g.x + 1.0f, gh = g.w - g.y + 1.0f;
    float gcx = g.x + 0.5f * gw, gcy = g.y + 0.5f * gh;
    o.x = (gcx - ecx) / ew;
    o.y = (gcy - ecy) / eh;
    o.z = logf(gw / ew);
    o.w = logf(gh / eh);
  }
  tout[(size_t)b * NANCH + a] = o;
}

// ---------------------------------------------------------------------------
extern "C" void kernel_launch(void* const* d_in, const int* in_sizes, int n_in,
                              void* d_out, int out_size, void* d_ws, size_t ws_size,
                              hipStream_t stream) {
  const float4* boxes  = (const float4*)d_in[0];
  const float4* gtb    = (const float4*)d_in[1];
  // d_in[2] = gt_labels: unused, exactly like the reference
  const int*    gti    = (const int*)d_in[3];
  const float*  iminfo = (const float*)d_in[4];
  float*  labels = (float*)d_out;                       // [B][N] as f32
  float4* tout   = (float4*)(labels + (size_t)NB * NANCH); // [B][N][4]

  char* wsb = (char*)d_ws;  // needs ~13.1 MB
  unsigned int*       g2a_u32  = (unsigned int*)(wsb + WS_G2A);
  float*              g2a_f    = (float*)(wsb + WS_G2A);
  int*                num_pos  = (int*)(wsb + WS_NUMPOS);
  int*                neg_cnt  = (int*)(wsb + WS_NEGCNT);
  unsigned long long* kth      = (unsigned long long*)(wsb + WS_KTH);
  int*                tbg      = (int*)(wsb + WS_TBG);
  int*                dosamp   = (int*)(wsb + WS_DOSAMP);
  unsigned long long* samp_key = (unsigned long long*)(wsb + WS_SAMPKEY);
  unsigned char*      a2g      = (unsigned char*)(wsb + WS_A2G);
  unsigned int*       neg_list = (unsigned int*)(wsb + WS_NEG);
  unsigned long long* pos_keys = (unsigned long long*)(wsb + WS_POS);

  // Host-side key derivation: root=(0,42); split(root,4) -> per-image key;
  // split(key_b,2) -> (kp, kn). Split keys are the FULL 64-bit outputs
  // (no XOR — _threefry_split_foldlike stacks both words).
  RngKeys rk;
  for (int b = 0; b < NB; ++b) {
    uint32_t a0, a1;
    tf_ctr(0u, 42u, (uint32_t)b, a0, a1);                // keys[b]
    tf_ctr(a0, a1, 0u, rk.kp[b][0], rk.kp[b][1]);        // subkey 0 = kp
    tf_ctr(a0, a1, 1u, rk.kn[b][0], rk.kn[b][1]);        // subkey 1 = kn
  }

  k_init   <<<18, 256, 0, stream>>>((unsigned int*)wsb);
  k_g2amax <<<NB * (NANCH / 1024), 256, 0, stream>>>(boxes, gtb, gti, iminfo, g2a_u32);
  k_label  <<<NB * (NANCH / 256), 256, 0, stream>>>(boxes, gtb, gti, iminfo, g2a_f,
                                                    labels, a2g, pos_keys, neg_list,
                                                    num_pos, neg_cnt, rk);
  k_select <<<NB, 256, 0, stream>>>(pos_keys, num_pos, neg_cnt, kth, tbg, dosamp);
  k_disable<<<NB * 64, 256, 0, stream>>>(pos_keys, num_pos, kth, labels);
  k_cat    <<<NB * (SB / SPT) * CC, 256, 0, stream>>>(neg_list, neg_cnt, samp_key, rk);
  k_scatter<<<NB * 2, 256, 0, stream>>>(samp_key, tbg, dosamp, labels);
  k_targets<<<NB * (NANCH / 256), 256, 0, stream>>>(boxes, gtb, a2g, labels, tout);
}